// Round 2
// baseline (227.905 us; speedup 1.0000x reference)
//
#include <hip/hip_runtime.h>

// out[r][c] = x[r][c] * weight[c] + bias[c]
// x: (8192, 4096) f32, weight/bias: (4096,) f32, out: (8192, 4096) f32.
// Memory-bound streaming. 268 MB of HBM traffic -> ~40 us floor at 6.7 TB/s.
//
// R2 = R1 with the nontemporal builtins fed a NATIVE clang vector type
// (ext_vector_type(4)) instead of HIP_vector_type<float,4>, which the
// builtin rejects.
//  - grid-stride loop at 2048 blocks (8 wg/CU), 16 iters/thread -> ILP.
//  - nontemporal load (x) / store (out): pure streaming, don't thrash L2.
//  - stride (524288) is a multiple of COLS4 (1024) -> c4 loop-invariant,
//    weight/bias loaded once per thread.

#define IN_SIZE   4096
#define COLS4     (IN_SIZE / 4)   // 1024
#define BLOCK     256
#define GRID      2048            // 256 CUs * 8 wg/CU; multiple of COLS4/BLOCK

typedef float f32x4 __attribute__((ext_vector_type(4)));

__global__ __launch_bounds__(BLOCK) void diag_linear_kernel(
    const f32x4* __restrict__ x,
    const f32x4* __restrict__ w,
    const f32x4* __restrict__ b,
    f32x4* __restrict__ out,
    int n4)  // total float4 elements
{
    const int tid    = blockIdx.x * BLOCK + threadIdx.x;
    const int stride = gridDim.x * BLOCK;   // 524288 = 512 * COLS4

    // stride % COLS4 == 0  =>  c4 invariant across the grid-stride loop.
    const int c4 = tid & (COLS4 - 1);
    const f32x4 wv = w[c4];
    const f32x4 bv = b[c4];

    #pragma unroll 4
    for (int idx = tid; idx < n4; idx += stride) {
        f32x4 xv = __builtin_nontemporal_load(x + idx);
        f32x4 o;
        o.x = fmaf(xv.x, wv.x, bv.x);
        o.y = fmaf(xv.y, wv.y, bv.y);
        o.z = fmaf(xv.z, wv.z, bv.z);
        o.w = fmaf(xv.w, wv.w, bv.w);
        __builtin_nontemporal_store(o, out + idx);
    }
}

extern "C" void kernel_launch(void* const* d_in, const int* in_sizes, int n_in,
                              void* d_out, int out_size, void* d_ws, size_t ws_size,
                              hipStream_t stream) {
    const f32x4* x = (const f32x4*)d_in[0];
    const f32x4* w = (const f32x4*)d_in[1];
    const f32x4* b = (const f32x4*)d_in[2];
    f32x4* out = (f32x4*)d_out;

    int n4 = out_size / 4;  // 8192*4096/4 = 8388608

    int grid = GRID;
    // Safety for small n4 (not hit at this problem size): shrink grid but
    // keep stride a multiple of COLS4 so the c4-invariance holds.
    int needed = (n4 + BLOCK - 1) / BLOCK;
    if (needed < grid) {
        grid = ((needed + (COLS4 / BLOCK) - 1) / (COLS4 / BLOCK)) * (COLS4 / BLOCK);
        if (grid < 1) grid = 1;
    }

    diag_linear_kernel<<<grid, BLOCK, 0, stream>>>(x, w, b, out, n4);
}